// Round 13
// baseline (6661.426 us; speedup 1.0000x reference)
//
#include <hip/hip_runtime.h>

#define TT 1024
#define BB 256
#define CC 41

__device__ __forceinline__ float sigf(float x) {
    float t = __builtin_amdgcn_exp2f(-1.4426950408889634f * x);
    return __builtin_amdgcn_rcpf(1.0f + t);
}
__device__ __forceinline__ float tanhf_fast(float x) {
    float t = __builtin_amdgcn_exp2f(2.8853900817779268f * x);
    return fmaf(-2.0f, __builtin_amdgcn_rcpf(t + 1.0f), 1.0f);
}
__device__ __forceinline__ float lane_bcast(float v, int k) {
    return __uint_as_float(__builtin_amdgcn_readlane(__float_as_uint(v), k));
}

// ---------------------------------------------------------------------------
// Quad-split fused LSTM. One (batch row, direction) per block, 1024 threads
// = 16 waves: wave w -> gate block gsel=w>>2 (64 gates = one act type),
// K-quarter qu=w&3. Per-thread weights wx[K/4]+wh[16] = 48 floats.
//
// WHY (round-12 counters): 16 waves/CU caps the unified reg file at 128/wave;
// the 2-way split demanded 96 weights + ~50 working = 146 > 128, so ~50
// weights could NEVER be resident -> the persistent 437 inst/step inflation
// (vs ~170 useful) that survived every allocator experiment (r5/7/8/9).
// 4-way split: demand ~95 <= 128 -> weights finally arch-resident at FULL
// 16-wave residency. Per-step work/wave halves; grid 512 (2 passes) but
// 2048 x ~half-step-wall < 1024 x current.
//
// Per step (ONE barrier, unroll x4 -> all LDS indices static):
//  - issue global prefetch of x_{s+2} (lands in slot (s+2)&3 pre-barrier)
//  - 16 ds_read partials (4 quarters x 4 act types for unit u=lane) + acts
//    + c/h update replicated per-lane (lane u of every wave = unit u)
//  - x-part: KQ/4 broadcast float4 LDS reads from slot s&3 + KQ FMAs
//  - h-part: 16x { readlane(hv, qu*16+j) ; fma }  (uniform lane index)
//  - write partial[s&1][qu][gate]; land prefetch; barrier
// ---------------------------------------------------------------------------
template <int K>
__global__ __launch_bounds__(1024, 4) void lstm_quad(
    const float* __restrict__ xin,   // [B,T,K]
    const float* __restrict__ w_ih,  // [2,256,K]
    const float* __restrict__ w_hh,  // [2,256,64]
    const float* __restrict__ bias,  // [2,256]
    float* __restrict__ hout)        // [B,T,128], dir writes its 64-half
{
    constexpr int KQ = ((K + 15) / 16) * 4;   // per-quarter length (mult of 4)
    constexpr int KP = 4 * KQ;                // padded x row length
    const int b = blockIdx.x;
    const int dir = blockIdx.y;
    const int tid = threadIdx.x;
    const int lane = tid & 63;
    const int w = tid >> 6;                        // 0..15 (wave-uniform)
    const int qu = __builtin_amdgcn_readfirstlane(w & 3);   // K-quarter, uniform
    const int gsel = w >> 2;                       // 0..3 = act block (i,f,g,o)
    const int G = gsel * 64 + lane;                // gate 0..255

    // ---- per-thread quarter-weights (48 floats: fits the 128-reg budget) ----
    float wx[KQ];
    {
        const float* wr = w_ih + ((size_t)dir * 256 + G) * K + qu * KQ;
#pragma unroll
        for (int j = 0; j < KQ; ++j)
            wx[j] = (qu * KQ + j < K) ? wr[j] : 0.f;   // pad tail (K=39)
    }
    float wh[16];
    {
        const float* hr = w_hh + ((size_t)dir * 256 + G) * 64 + qu * 16;
#pragma unroll
        for (int j = 0; j < 16; ++j) wh[j] = hr[j];
    }
    const float bg = qu ? 0.f : bias[dir * 256 + G];

    __shared__ __align__(16) float xs[4][KP];     // 4-slot rotating x staging
    __shared__ float part[2][4][256];             // [parity][quarter][gate]

    const float* xb = xin + (size_t)b * TT * K;
    float* hob = hout + (size_t)b * TT * 128 + dir * 64;

    // prologue: stage x for s=0,1; zero pad lanes of all slots; zero part[1]
    // so step-0's "previous update" is a no-op (keeps c=h=0).
    if (tid < K) {
        const int t0 = dir ? (TT - 1) : 0;
        const int t1 = dir ? (TT - 2) : 1;
        xs[0][tid] = xb[(size_t)t0 * K + tid];
        xs[1][tid] = xb[(size_t)t1 * K + tid];
    }
    if (KP > K && tid >= K && tid < KP) {
        xs[0][tid] = 0.f; xs[1][tid] = 0.f; xs[2][tid] = 0.f; xs[3][tid] = 0.f;
    }
    (&part[1][0][0])[tid] = 0.f;   // 1024 floats = part[1] entirely

    float c = 0.f, hv = 0.f;
    __syncthreads();

    for (int sb = 0; sb < TT; sb += 4) {
#pragma unroll
        for (int U = 0; U < 4; ++U) {
            const int s = sb + U;   // sb%4==0 -> s&3==U, s&1==U&1 (static)

            // ---- issue prefetch of x_{s+2} (lands before the barrier) ----
            const bool pf = (s + 2 < TT) && (tid < K);
            float xf = 0.f;
            if (pf) {
                const int tp = dir ? (TT - 3 - s) : (s + 2);
                xf = xb[(size_t)tp * K + tid];
            }

            // ---- previous step's partials (4 quarters x 4 act types) ----
            const float* pp = &part[(s + 1) & 1][0][0];
            const float ai = (pp[lane]       + pp[256 + lane]) +
                             (pp[512 + lane] + pp[768 + lane]);
            const float af = (pp[64 + lane]       + pp[256 + 64 + lane]) +
                             (pp[512 + 64 + lane] + pp[768 + 64 + lane]);
            const float ag = (pp[128 + lane]       + pp[256 + 128 + lane]) +
                             (pp[512 + 128 + lane] + pp[768 + 128 + lane]);
            const float ao = (pp[192 + lane]       + pp[256 + 192 + lane]) +
                             (pp[512 + 192 + lane] + pp[768 + 192 + lane]);
            const float iv = sigf(ai), fv = sigf(af);
            const float gv = tanhf_fast(ag), ov = sigf(ao);
            c = fmaf(fv, c, iv * gv);
            hv = ov * tanhf_fast(c);
            if (s && w == 0) {
                const int tprev = dir ? (TT - s) : (s - 1);
                hob[(size_t)tprev * 128 + lane] = hv;   // fire-and-forget
            }

            // ---- x-part: broadcast float4 reads of this wave's K-quarter ----
            float ap0 = bg, ap1 = 0.f, ap2 = 0.f, ap3 = 0.f;
            const float4* xv4 = (const float4*)(xs[s & 3] + qu * KQ);
#pragma unroll
            for (int q = 0; q < KQ / 4; ++q) {
                const float4 xv = xv4[q];
                ap0 = fmaf(xv.x, wx[4 * q + 0], ap0);
                ap1 = fmaf(xv.y, wx[4 * q + 1], ap1);
                ap2 = fmaf(xv.z, wx[4 * q + 2], ap2);
                ap3 = fmaf(xv.w, wx[4 * q + 3], ap3);
            }

            // ---- h-part: readlane broadcast, k = qu*16 + j (uniform) ----
#pragma unroll
            for (int j = 0; j < 16; ++j) {
                const float hk = lane_bcast(hv, qu * 16 + j);
                if ((j & 3) == 0)      ap0 = fmaf(hk, wh[j], ap0);
                else if ((j & 3) == 1) ap1 = fmaf(hk, wh[j], ap1);
                else if ((j & 3) == 2) ap2 = fmaf(hk, wh[j], ap2);
                else                   ap3 = fmaf(hk, wh[j], ap3);
            }

            // ---- this step's partial ----
            part[s & 1][qu][G] = (ap0 + ap1) + (ap2 + ap3);

            // ---- land prefetched x in slot (s+2)&3 (static) ----
            if (pf) xs[(s + 2) & 3][tid] = xf;
            __syncthreads();
        }
    }

    // epilogue: h[TT-1] from the last partials
    {
        const float* pp = &part[(TT - 1) & 1][0][0];
        const float ai = (pp[lane]       + pp[256 + lane]) +
                         (pp[512 + lane] + pp[768 + lane]);
        const float af = (pp[64 + lane]       + pp[256 + 64 + lane]) +
                         (pp[512 + 64 + lane] + pp[768 + 64 + lane]);
        const float ag = (pp[128 + lane]       + pp[256 + 128 + lane]) +
                         (pp[512 + 128 + lane] + pp[768 + 128 + lane]);
        const float ao = (pp[192 + lane]       + pp[256 + 192 + lane]) +
                         (pp[512 + 192 + lane] + pp[768 + 192 + lane]);
        const float cf = fmaf(sigf(af), c, sigf(ai) * tanhf_fast(ag));
        const float hf = sigf(ao) * tanhf_fast(cf);
        if (w == 0) {
            const int tlast = dir ? 0 : (TT - 1);
            hob[(size_t)tlast * 128 + lane] = hf;
        }
    }
}

// emissions = feats @ lin_w^T + lin_b ; block tile = 64 (b,t) rows x 41 classes
__global__ __launch_bounds__(256, 2) void emis_kernel(
    const float* __restrict__ feats,  // [B*T,128]
    const float* __restrict__ lw,     // [41,128]
    const float* __restrict__ lb,     // [41]
    float* __restrict__ e)            // [B*T,41]
{
    __shared__ float sf[64 * 132];
    __shared__ float swt[41 * 132];
    const int tid = threadIdx.x;
    const size_t bt0 = (size_t)blockIdx.x * 64;

    const float4* fs = (const float4*)(feats + bt0 * 128);
#pragma unroll
    for (int q = 0; q < 8; ++q) {
        const int idx = tid + q * 256;
        const int row = idx >> 5, col = idx & 31;
        *(float4*)&sf[row * 132 + col * 4] = fs[idx];
    }
    for (int idx = tid; idx < 41 * 32; idx += 256) {
        const int row = idx >> 5, col = idx & 31;
        *(float4*)&swt[row * 132 + col * 4] = ((const float4*)lw)[idx];
    }
    __syncthreads();

    const int btg = tid >> 4;
    const int cg = tid & 15;
    const int c0 = cg * 3;
    float acc[4][3];
#pragma unroll
    for (int i = 0; i < 4; ++i)
#pragma unroll
        for (int j = 0; j < 3; ++j) acc[i][j] = 0.f;

    for (int k = 0; k < 128; k += 4) {
        float4 fv[4], wv[3];
#pragma unroll
        for (int i = 0; i < 4; ++i) fv[i] = *(const float4*)&sf[(btg * 4 + i) * 132 + k];
#pragma unroll
        for (int j = 0; j < 3; ++j) {
            const int c = (c0 + j < CC) ? (c0 + j) : (CC - 1);
            wv[j] = *(const float4*)&swt[c * 132 + k];
        }
#pragma unroll
        for (int i = 0; i < 4; ++i)
#pragma unroll
            for (int j = 0; j < 3; ++j) {
                acc[i][j] = fmaf(fv[i].x, wv[j].x, acc[i][j]);
                acc[i][j] = fmaf(fv[i].y, wv[j].y, acc[i][j]);
                acc[i][j] = fmaf(fv[i].z, wv[j].z, acc[i][j]);
                acc[i][j] = fmaf(fv[i].w, wv[j].w, acc[i][j]);
            }
    }
    __syncthreads();
    float* so = sf;
#pragma unroll
    for (int i = 0; i < 4; ++i)
#pragma unroll
        for (int j = 0; j < 3; ++j) {
            const int c = c0 + j;
            if (c < CC) so[(btg * 4 + i) * CC + c] = acc[i][j] + lb[c];
        }
    __syncthreads();
    float* eo = e + bt0 * CC;
    for (int q = tid; q < 64 * CC; q += 256) eo[q] = so[q];
}

// One wave per batch row; backpointers in LDS; in-kernel backtrace.
__global__ __launch_bounds__(64, 1) void viterbi_kernel(
    const float* __restrict__ e, const float* __restrict__ st,
    const float* __restrict__ en, const float* __restrict__ tr,
    int* __restrict__ out)
{
    const int b = blockIdx.x;
    const int lane = threadIdx.x;
    __shared__ unsigned char bp[TT][CC];
    __shared__ float sc[2][CC];
    const int c = (lane < CC) ? lane : (CC - 1);
    float trc[CC];
#pragma unroll
    for (int p = 0; p < CC; ++p) trc[p] = tr[p * CC + c];

    const float* eb = e + (size_t)b * TT * CC;
    const float NEG = -3.0e38f;
    if (lane < CC) sc[0][lane] = st[lane] + eb[lane];
    __syncthreads();

    for (int t = 1; t < TT; ++t) {
        const float* scp = sc[(t - 1) & 1];
        float best = NEG;
        int bi = 0;
#pragma unroll
        for (int p = 0; p < CC; ++p) {
            const float v = scp[p] + trc[p];
            if (v > best) { best = v; bi = p; }   // strict > : first-index ties
        }
        if (lane < CC) {
            sc[t & 1][lane] = best + eb[(size_t)t * CC + lane];
            bp[t][lane] = (unsigned char)bi;
        }
        __syncthreads();
    }

    float fin = (lane < CC) ? sc[(TT - 1) & 1][lane] + en[lane] : NEG;
    int idx = lane;
#pragma unroll
    for (int off = 32; off; off >>= 1) {
        const float v2 = __shfl_down(fin, off, 64);
        const int i2 = __shfl_down(idx, off, 64);
        if (v2 > fin || (v2 == fin && i2 < idx)) { fin = v2; idx = i2; }
    }
    int tag = __shfl(idx, 0, 64);
    if (lane == 0) {
        int* ob = out + (size_t)b * TT;
        ob[TT - 1] = tag;
        for (int t = TT - 1; t >= 1; --t) {
            tag = bp[t][tag];
            ob[t - 1] = tag;
        }
    }
}

extern "C" void kernel_launch(void* const* d_in, const int* in_sizes, int n_in,
                              void* d_out, int out_size, void* d_ws, size_t ws_size,
                              hipStream_t stream) {
    const float* x       = (const float*)d_in[0];   // [B,T,39]
    const float* w_ih_l0 = (const float*)d_in[1];   // [2,256,39]
    const float* w_hh_l0 = (const float*)d_in[2];   // [2,256,64]
    const float* b_l0    = (const float*)d_in[3];   // [2,256]
    const float* w_ih_r  = (const float*)d_in[4];   // [2,2,256,128]
    const float* w_hh_r  = (const float*)d_in[5];   // [2,2,256,64]
    const float* b_r     = (const float*)d_in[6];   // [2,2,256]
    const float* lin_w   = (const float*)d_in[7];   // [41,128]
    const float* lin_b   = (const float*)d_in[8];   // [41]
    const float* crf_s   = (const float*)d_in[9];   // [41]
    const float* crf_e   = (const float*)d_in[10];  // [41]
    const float* crf_t   = (const float*)d_in[11];  // [41,41]
    int* out = (int*)d_out;

    float* buf0 = (float*)d_ws;                         // [B,T,128] = 128 MiB
    float* buf1 = buf0 + (size_t)BB * TT * 128;         // [B,T,128] = 128 MiB

    dim3 grid(BB, 2);
    // layer 0 (input dim 39): buf0 <- x
    lstm_quad<39><<<grid, 1024, 0, stream>>>(x, w_ih_l0, w_hh_l0, b_l0, buf0);
    // layer 1: buf1 <- buf0
    lstm_quad<128><<<grid, 1024, 0, stream>>>(buf0, w_ih_r, w_hh_r, b_r, buf1);
    // layer 2: buf0 <- buf1
    lstm_quad<128><<<grid, 1024, 0, stream>>>(
        buf1, w_ih_r + 2 * 256 * 128, w_hh_r + 2 * 256 * 64, b_r + 2 * 256, buf0);
    // emissions: buf1 <- buf0, [B*T,41]
    emis_kernel<<<BB * TT / 64, 256, 0, stream>>>(buf0, lin_w, lin_b, buf1);
    // viterbi + backtrace
    viterbi_kernel<<<BB, 64, 0, stream>>>(buf1, crf_s, crf_e, crf_t, out);
}

// Round 14
// 5255.489 us; speedup vs baseline: 1.2675x; 1.2675x over previous
//
#include <hip/hip_runtime.h>

#define TT 1024
#define BB 256
#define CC 41

__device__ __forceinline__ float sigf(float x) {
    float t = __builtin_amdgcn_exp2f(-1.4426950408889634f * x);
    return __builtin_amdgcn_rcpf(1.0f + t);
}
__device__ __forceinline__ float tanhf_fast(float x) {
    float t = __builtin_amdgcn_exp2f(2.8853900817779268f * x);
    return fmaf(-2.0f, __builtin_amdgcn_rcpf(t + 1.0f), 1.0f);
}
__device__ __forceinline__ float lane_bcast(float v, int k) {
    return __uint_as_float(__builtin_amdgcn_readlane(__float_as_uint(v), k));
}

// ---------------------------------------------------------------------------
// Dual-direction split-K fused LSTM (round-12 structure -- the measured
// optimum of this design family: 1757us/layer, occupancy 47.7%, VALU 85%).
// ONE batch row per block, BOTH directions: 1024 threads = 16 waves; waves
// 0-7 run dir0, waves 8-15 run dir1, each wave = (gate block gsel, K-half).
// The two dir-streams are independent and share only the block barrier.
//
// Split-degree trade, measured: 1-way (r0: 2600cyc/step, 2 passes),
// 2-way dual (r12: 4120cyc/step, 1 pass), 4-way (r13: 2788cyc/step,
// 2 passes). Dual wins: the per-step latency floor (~500cyc: barrier,
// ds_read latency, replicated act chain) is split-invariant, so more work
// per step + one pass amortizes it best.
//
// Step-loop unroll x4: all LDS indices compile-time static.
// ---------------------------------------------------------------------------
template <int K>
__global__ __launch_bounds__(1024, 4) void lstm_dual(
    const float* __restrict__ xin,   // [B,T,K]
    const float* __restrict__ w_ih,  // [2,256,K]
    const float* __restrict__ w_hh,  // [2,256,64]
    const float* __restrict__ bias,  // [2,256]
    float* __restrict__ hout)        // [B,T,128], dir writes its 64-half
{
    constexpr int KH = ((K + 7) / 8) * 4;   // per-half K length (mult of 4)
    constexpr int KP = 2 * KH;              // padded x row length
    const int b = blockIdx.x;
    const int tid = threadIdx.x;
    const int t512 = tid & 511;                    // index within dir-half
    const int lane = tid & 63;
    const int w8 = t512 >> 6;                      // 0..7 (wave-uniform)
    const int diru = __builtin_amdgcn_readfirstlane(tid >> 9);   // 0/1 uniform
    const int halfu = __builtin_amdgcn_readfirstlane(w8 & 1);    // uniform
    const int gsel = w8 >> 1;                      // 0..3 = act block (i,f,g,o)
    const int G = gsel * 64 + lane;                // gate 0..255

    // ---- per-thread half-weights ----
    float wx[KH];
    {
        const float* wr = w_ih + ((size_t)diru * 256 + G) * K + halfu * KH;
#pragma unroll
        for (int j = 0; j < KH; ++j)
            wx[j] = (halfu * KH + j < K) ? wr[j] : 0.f;   // pad tail (K=39)
    }
    float wh[32];
    {
        const float* hr = w_hh + ((size_t)diru * 256 + G) * 64 + halfu * 32;
#pragma unroll
        for (int j = 0; j < 32; ++j) wh[j] = hr[j];
    }
    const float bg = halfu ? 0.f : bias[diru * 256 + G];

    __shared__ __align__(16) float xs[2][4][KP];   // per-dir 4-slot x staging
    __shared__ float part[2][2][2][256];           // [dir][parity][half][gate]

    const float* xb = xin + (size_t)b * TT * K;
    float* hob = hout + (size_t)b * TT * 128 + diru * 64;

    // prologue: each dir stages its own x(s=0,1); zero pads; zero its part[1]
    // so step-0's "previous update" is a no-op (keeps c=h=0).
    if (t512 < K) {
        const int t0 = diru ? (TT - 1) : 0;
        const int t1 = diru ? (TT - 2) : 1;
        xs[diru][0][t512] = xb[(size_t)t0 * K + t512];
        xs[diru][1][t512] = xb[(size_t)t1 * K + t512];
    }
    if (KP > K && t512 >= K && t512 < KP) {
        xs[diru][0][t512] = 0.f; xs[diru][1][t512] = 0.f;
        xs[diru][2][t512] = 0.f; xs[diru][3][t512] = 0.f;
    }
    (&part[diru][1][0][0])[t512] = 0.f;   // each dir zeroes its 512 floats

    float c = 0.f, hv = 0.f;
    __syncthreads();

    for (int sb = 0; sb < TT; sb += 4) {
#pragma unroll
        for (int U = 0; U < 4; ++U) {
            const int s = sb + U;   // sb%4==0 -> s&3==U, s&1==U&1 (static)

            // ---- issue prefetch of x_{s+2} (lands before the barrier) ----
            const bool pf = (s + 2 < TT) && (t512 < K);
            float xf = 0.f;
            if (pf) {
                const int tp = diru ? (TT - 3 - s) : (s + 2);
                xf = xb[(size_t)tp * K + t512];
            }

            // ---- previous step's partials -> acts for unit u=lane ----
            const float* pp0 = part[diru][(s + 1) & 1][0];
            const float* pp1 = part[diru][(s + 1) & 1][1];
            const float ai = pp0[lane]       + pp1[lane];
            const float af = pp0[64 + lane]  + pp1[64 + lane];
            const float ag = pp0[128 + lane] + pp1[128 + lane];
            const float ao = pp0[192 + lane] + pp1[192 + lane];
            const float iv = sigf(ai), fv = sigf(af);
            const float gv = tanhf_fast(ag), ov = sigf(ao);
            c = fmaf(fv, c, iv * gv);
            hv = ov * tanhf_fast(c);
            if (s && w8 == 0) {   // wave 0 of each dir-half stores its h
                const int tprev = diru ? (TT - s) : (s - 1);
                hob[(size_t)tprev * 128 + lane] = hv;   // fire-and-forget
            }

            // ---- x-part: broadcast float4 reads of this wave's K-half ----
            float ap0 = bg, ap1 = 0.f, ap2 = 0.f, ap3 = 0.f;
            const float4* xv4 = (const float4*)(xs[diru][s & 3] + halfu * KH);
#pragma unroll
            for (int q = 0; q < KH / 4; ++q) {
                const float4 xv = xv4[q];
                ap0 = fmaf(xv.x, wx[4 * q + 0], ap0);
                ap1 = fmaf(xv.y, wx[4 * q + 1], ap1);
                ap2 = fmaf(xv.z, wx[4 * q + 2], ap2);
                ap3 = fmaf(xv.w, wx[4 * q + 3], ap3);
            }

            // ---- h-part: readlane broadcast, k = halfu*32 + j (uniform) ----
#pragma unroll
            for (int j = 0; j < 32; ++j) {
                const float hk = lane_bcast(hv, halfu * 32 + j);
                if ((j & 3) == 0)      ap0 = fmaf(hk, wh[j], ap0);
                else if ((j & 3) == 1) ap1 = fmaf(hk, wh[j], ap1);
                else if ((j & 3) == 2) ap2 = fmaf(hk, wh[j], ap2);
                else                   ap3 = fmaf(hk, wh[j], ap3);
            }

            // ---- this step's partial ----
            part[diru][s & 1][halfu][G] = (ap0 + ap1) + (ap2 + ap3);

            // ---- land prefetched x in slot (s+2)&3 (static) ----
            if (pf) xs[diru][(s + 2) & 3][t512] = xf;
            __syncthreads();
        }
    }

    // epilogue: h[TT-1] from the last partials
    {
        const float* pp0 = part[diru][(TT - 1) & 1][0];
        const float* pp1 = part[diru][(TT - 1) & 1][1];
        const float ai = pp0[lane]       + pp1[lane];
        const float af = pp0[64 + lane]  + pp1[64 + lane];
        const float ag = pp0[128 + lane] + pp1[128 + lane];
        const float ao = pp0[192 + lane] + pp1[192 + lane];
        const float cf = fmaf(sigf(af), c, sigf(ai) * tanhf_fast(ag));
        const float hf = sigf(ao) * tanhf_fast(cf);
        if (w8 == 0) {
            const int tlast = diru ? 0 : (TT - 1);
            hob[(size_t)tlast * 128 + lane] = hf;
        }
    }
}

// emissions = feats @ lin_w^T + lin_b ; block tile = 64 (b,t) rows x 41 classes
__global__ __launch_bounds__(256, 2) void emis_kernel(
    const float* __restrict__ feats,  // [B*T,128]
    const float* __restrict__ lw,     // [41,128]
    const float* __restrict__ lb,     // [41]
    float* __restrict__ e)            // [B*T,41]
{
    __shared__ float sf[64 * 132];
    __shared__ float swt[41 * 132];
    const int tid = threadIdx.x;
    const size_t bt0 = (size_t)blockIdx.x * 64;

    const float4* fs = (const float4*)(feats + bt0 * 128);
#pragma unroll
    for (int q = 0; q < 8; ++q) {
        const int idx = tid + q * 256;
        const int row = idx >> 5, col = idx & 31;
        *(float4*)&sf[row * 132 + col * 4] = fs[idx];
    }
    for (int idx = tid; idx < 41 * 32; idx += 256) {
        const int row = idx >> 5, col = idx & 31;
        *(float4*)&swt[row * 132 + col * 4] = ((const float4*)lw)[idx];
    }
    __syncthreads();

    const int btg = tid >> 4;
    const int cg = tid & 15;
    const int c0 = cg * 3;
    float acc[4][3];
#pragma unroll
    for (int i = 0; i < 4; ++i)
#pragma unroll
        for (int j = 0; j < 3; ++j) acc[i][j] = 0.f;

    for (int k = 0; k < 128; k += 4) {
        float4 fv[4], wv[3];
#pragma unroll
        for (int i = 0; i < 4; ++i) fv[i] = *(const float4*)&sf[(btg * 4 + i) * 132 + k];
#pragma unroll
        for (int j = 0; j < 3; ++j) {
            const int c = (c0 + j < CC) ? (c0 + j) : (CC - 1);
            wv[j] = *(const float4*)&swt[c * 132 + k];
        }
#pragma unroll
        for (int i = 0; i < 4; ++i)
#pragma unroll
            for (int j = 0; j < 3; ++j) {
                acc[i][j] = fmaf(fv[i].x, wv[j].x, acc[i][j]);
                acc[i][j] = fmaf(fv[i].y, wv[j].y, acc[i][j]);
                acc[i][j] = fmaf(fv[i].z, wv[j].z, acc[i][j]);
                acc[i][j] = fmaf(fv[i].w, wv[j].w, acc[i][j]);
            }
    }
    __syncthreads();
    float* so = sf;
#pragma unroll
    for (int i = 0; i < 4; ++i)
#pragma unroll
        for (int j = 0; j < 3; ++j) {
            const int c = c0 + j;
            if (c < CC) so[(btg * 4 + i) * CC + c] = acc[i][j] + lb[c];
        }
    __syncthreads();
    float* eo = e + bt0 * CC;
    for (int q = tid; q < 64 * CC; q += 256) eo[q] = so[q];
}

// One wave per batch row; backpointers in LDS; in-kernel backtrace.
__global__ __launch_bounds__(64, 1) void viterbi_kernel(
    const float* __restrict__ e, const float* __restrict__ st,
    const float* __restrict__ en, const float* __restrict__ tr,
    int* __restrict__ out)
{
    const int b = blockIdx.x;
    const int lane = threadIdx.x;
    __shared__ unsigned char bp[TT][CC];
    __shared__ float sc[2][CC];
    const int c = (lane < CC) ? lane : (CC - 1);
    float trc[CC];
#pragma unroll
    for (int p = 0; p < CC; ++p) trc[p] = tr[p * CC + c];

    const float* eb = e + (size_t)b * TT * CC;
    const float NEG = -3.0e38f;
    if (lane < CC) sc[0][lane] = st[lane] + eb[lane];
    __syncthreads();

    for (int t = 1; t < TT; ++t) {
        const float* scp = sc[(t - 1) & 1];
        float best = NEG;
        int bi = 0;
#pragma unroll
        for (int p = 0; p < CC; ++p) {
            const float v = scp[p] + trc[p];
            if (v > best) { best = v; bi = p; }   // strict > : first-index ties
        }
        if (lane < CC) {
            sc[t & 1][lane] = best + eb[(size_t)t * CC + lane];
            bp[t][lane] = (unsigned char)bi;
        }
        __syncthreads();
    }

    float fin = (lane < CC) ? sc[(TT - 1) & 1][lane] + en[lane] : NEG;
    int idx = lane;
#pragma unroll
    for (int off = 32; off; off >>= 1) {
        const float v2 = __shfl_down(fin, off, 64);
        const int i2 = __shfl_down(idx, off, 64);
        if (v2 > fin || (v2 == fin && i2 < idx)) { fin = v2; idx = i2; }
    }
    int tag = __shfl(idx, 0, 64);
    if (lane == 0) {
        int* ob = out + (size_t)b * TT;
        ob[TT - 1] = tag;
        for (int t = TT - 1; t >= 1; --t) {
            tag = bp[t][tag];
            ob[t - 1] = tag;
        }
    }
}

extern "C" void kernel_launch(void* const* d_in, const int* in_sizes, int n_in,
                              void* d_out, int out_size, void* d_ws, size_t ws_size,
                              hipStream_t stream) {
    const float* x       = (const float*)d_in[0];   // [B,T,39]
    const float* w_ih_l0 = (const float*)d_in[1];   // [2,256,39]
    const float* w_hh_l0 = (const float*)d_in[2];   // [2,256,64]
    const float* b_l0    = (const float*)d_in[3];   // [2,256]
    const float* w_ih_r  = (const float*)d_in[4];   // [2,2,256,128]
    const float* w_hh_r  = (const float*)d_in[5];   // [2,2,256,64]
    const float* b_r     = (const float*)d_in[6];   // [2,2,256]
    const float* lin_w   = (const float*)d_in[7];   // [41,128]
    const float* lin_b   = (const float*)d_in[8];   // [41]
    const float* crf_s   = (const float*)d_in[9];   // [41]
    const float* crf_e   = (const float*)d_in[10];  // [41]
    const float* crf_t   = (const float*)d_in[11];  // [41,41]
    int* out = (int*)d_out;

    float* buf0 = (float*)d_ws;                         // [B,T,128] = 128 MiB
    float* buf1 = buf0 + (size_t)BB * TT * 128;         // [B,T,128] = 128 MiB

    // 256 blocks (one per batch row, both dirs inside) = exactly 1 block/CU
    // layer 0 (input dim 39): buf0 <- x
    lstm_dual<39><<<BB, 1024, 0, stream>>>(x, w_ih_l0, w_hh_l0, b_l0, buf0);
    // layer 1: buf1 <- buf0
    lstm_dual<128><<<BB, 1024, 0, stream>>>(buf0, w_ih_r, w_hh_r, b_r, buf1);
    // layer 2: buf0 <- buf1
    lstm_dual<128><<<BB, 1024, 0, stream>>>(
        buf1, w_ih_r + 2 * 256 * 128, w_hh_r + 2 * 256 * 64, b_r + 2 * 256, buf0);
    // emissions: buf1 <- buf0, [B*T,41]
    emis_kernel<<<BB * TT / 64, 256, 0, stream>>>(buf0, lin_w, lin_b, buf1);
    // viterbi + backtrace
    viterbi_kernel<<<BB, 64, 0, stream>>>(buf1, crf_s, crf_e, crf_t, out);
}